// Round 22
// baseline (335.779 us; speedup 1.0000x reference)
//
#include <hip/hip_runtime.h>
#include <hip/hip_bf16.h>
#include <stdint.h>

#define Tn 2048
#define Dn 1024
#define DKn 512
#define Hn 2
#define Bn 8
#define BT (Bn*Tn)   // 16384
#define QKVS 3072

typedef __attribute__((ext_vector_type(8))) short bf16x8;
typedef __attribute__((ext_vector_type(4))) float f32x4;
typedef __attribute__((ext_vector_type(8))) unsigned short u16x8;

__device__ inline unsigned short f2bf(float f){
  unsigned u = __float_as_uint(f);
  u += 0x7fff + ((u >> 16) & 1);
  return (unsigned short)(u >> 16);
}
__device__ inline float bf2f(unsigned short u){
  return __uint_as_float(((unsigned)u) << 16);
}

// ---------------- fused cast: x|Wq|Wk|Wv|Wo -> contiguous bf16 region ----------------
__global__ __launch_bounds__(256) void cast_all_k(const float* __restrict__ x,
    const float* __restrict__ wq, const float* __restrict__ wk,
    const float* __restrict__ wv, const float* __restrict__ wo,
    unsigned short* __restrict__ out){
  int i = blockIdx.x*256 + threadIdx.x;   // 0..5242879
  const float* src; unsigned off;
  if      (i < 4194304){ src = x;  off = i; }
  else if (i < 4456448){ src = wq; off = i - 4194304; }
  else if (i < 4718592){ src = wk; off = i - 4456448; }
  else if (i < 4980736){ src = wv; off = i - 4718592; }
  else                 { src = wo; off = i - 4980736; }
  float4 f = ((const float4*)src)[off];
  ushort4 o;
  o.x = f2bf(f.x); o.y = f2bf(f.y); o.z = f2bf(f.z); o.w = f2bf(f.w);
  ((ushort4*)out)[i] = o;
}

#define GLOAD(src, dst) __builtin_amdgcn_global_load_lds( \
    (const __attribute__((address_space(1))) uint32_t*)(src), \
    (__attribute__((address_space(3))) uint32_t*)(dst), 16, 0, 0)

// ---------------- bf16 NT GEMM: 256x128 tile, 3-ring LDS, 1 barrier/K-tile ----------
// (unchanged from rounds 17-21 — verified passing at 911 TF)
template<bool BF16OUT>
__global__ __launch_bounds__(512) void gemm_3r(const unsigned short* __restrict__ A,
                                               const unsigned short* __restrict__ B,
                                               void* __restrict__ Cv, int M, int N, int K){
  __shared__ unsigned short As[3][256*64];
  __shared__ unsigned short Bs[3][128*64];
  const int tid  = threadIdx.x;
  const int lane = tid & 63;
  const int wid  = tid >> 6;          // 0..7
  const int wm = wid >> 1;            // 0..3 (64-row m group)
  const int wn = wid & 1;             // 0..1 (64-col n group)

  const int nmb = M >> 8, mpx = nmb >> 3;
  const int xcd = blockIdx.x & 7;
  const int lid = blockIdx.x >> 3;
  const int m0 = (xcd*mpx + (lid % mpx)) << 8;   // m-fastest within XCD chunk
  const int n0 = (lid / mpx) << 7;

  const int l15 = lane & 15, g4 = lane >> 4;
  const int r7  = l15 & 7;
  const int strow = tid >> 3;                       // 0..63
  const int stcol = (((tid & 7) ^ (strow & 7)) << 3);

  const unsigned short* pa[4];
  const unsigned short* pb[2];
  #pragma unroll
  for (int i=0;i<4;i++) pa[i] = A + (size_t)(m0 + i*64 + strow)*K + stcol;
  #pragma unroll
  for (int i=0;i<2;i++) pb[i] = B + (size_t)(n0 + i*64 + strow)*K + stcol;

  const int aoff = (wm*64 + l15)*64 + ((g4 ^ r7) << 3);
  const int boff = (wn*64 + l15)*64 + ((g4 ^ r7) << 3);
  const int aoffx = aoff ^ 32;    // ks=1 granule: (4+g4)^r7 on full offset
  const int boffx = boff ^ 32;
  const unsigned short* rA0  = &As[0][aoff];
  const unsigned short* rA1  = &As[1][aoff];
  const unsigned short* rA2  = &As[2][aoff];
  const unsigned short* rAx0 = &As[0][aoffx];
  const unsigned short* rAx1 = &As[1][aoffx];
  const unsigned short* rAx2 = &As[2][aoffx];
  const unsigned short* rB0  = &Bs[0][boff];
  const unsigned short* rB1  = &Bs[1][boff];
  const unsigned short* rB2  = &Bs[2][boff];
  const unsigned short* rBx0 = &Bs[0][boffx];
  const unsigned short* rBx1 = &Bs[1][boffx];
  const unsigned short* rBx2 = &Bs[2][boffx];
  unsigned short* sA0 = &As[0][tid*8];
  unsigned short* sA1 = &As[1][tid*8];
  unsigned short* sA2 = &As[2][tid*8];
  unsigned short* sB0 = &Bs[0][tid*8];
  unsigned short* sB1 = &Bs[1][tid*8];
  unsigned short* sB2 = &Bs[2][tid*8];

  f32x4 acc[4][4];
  #pragma unroll
  for (int m=0;m<4;m++)
    #pragma unroll
    for (int n=0;n<4;n++) acc[m][n] = (f32x4){0.f,0.f,0.f,0.f};

  const int NT = K >> 6;

#define STG3(SA, SB, kt) { \
    _Pragma("unroll") \
    for (int i_=0;i_<4;i_++) GLOAD(pa[i_] + (size_t)(kt)*64, (SA) + i_*4096); \
    _Pragma("unroll") \
    for (int i_=0;i_<2;i_++) GLOAD(pb[i_] + (size_t)(kt)*64, (SB) + i_*4096); \
  }

#define BODY(RA, RAX, RB, RBX, SA2_, SB2_, t) { \
    bf16x8 af[4][2], bfr[4][2]; \
    _Pragma("unroll") \
    for (int mf=0;mf<4;mf++){ \
      af[mf][0] = *(const bf16x8*)((RA)  + mf*1024); \
      af[mf][1] = *(const bf16x8*)((RAX) + mf*1024); \
    } \
    _Pragma("unroll") \
    for (int nf=0;nf<4;nf++){ \
      bfr[nf][0] = *(const bf16x8*)((RB)  + nf*1024); \
      bfr[nf][1] = *(const bf16x8*)((RBX) + nf*1024); \
    } \
    if ((t)+2 < NT) STG3(SA2_, SB2_, (t)+2) \
    __builtin_amdgcn_s_setprio(1); \
    _Pragma("unroll") \
    for (int ks=0;ks<2;ks++) \
      _Pragma("unroll") \
      for (int mf=0;mf<4;mf++) \
        _Pragma("unroll") \
        for (int nf=0;nf<4;nf++) \
          acc[mf][nf] = __builtin_amdgcn_mfma_f32_16x16x32_bf16(af[mf][ks], bfr[nf][ks], acc[mf][nf], 0,0,0); \
    __builtin_amdgcn_s_setprio(0); \
    if ((t) < NT-1){ \
      if ((t) < NT-2) asm volatile("s_waitcnt vmcnt(6) lgkmcnt(0)\n\ts_barrier" ::: "memory"); \
      else            asm volatile("s_waitcnt vmcnt(0) lgkmcnt(0)\n\ts_barrier" ::: "memory"); \
    } \
  }

  STG3(sA0, sB0, 0)
  STG3(sA1, sB1, 1)
  asm volatile("s_waitcnt vmcnt(6)\n\ts_barrier" ::: "memory");

  for (int tt=0; tt<15; tt+=3){
    BODY(rA0, rAx0, rB0, rBx0, sA2, sB2, tt)
    BODY(rA1, rAx1, rB1, rBx1, sA0, sB0, tt+1)
    BODY(rA2, rAx2, rB2, rBx2, sA1, sB1, tt+2)
  }
  BODY(rA0, rAx0, rB0, rBx0, sA2, sB2, 15)
#undef BODY
#undef STG3

  const int crow = (lane >> 4) * 4;
  const int ccol = (lane & 15);
  #pragma unroll
  for (int mf=0;mf<4;mf++)
    #pragma unroll
    for (int nf=0;nf<4;nf++)
      #pragma unroll
      for (int r=0;r<4;r++){
        size_t idx = (size_t)(m0 + wm*64 + mf*16 + crow + r)*N + (n0 + wn*64 + nf*16 + ccol);
        if constexpr (BF16OUT) ((unsigned short*)Cv)[idx] = f2bf(acc[mf][nf][r]);
        else                   ((float*)Cv)[idx] = acc[mf][nf][r];
      }
}

// ---------------- gates2: single k pass (kn via LDS transpose) + gates ----------------
// (unchanged from round 21 — verified)
__global__ __launch_bounds__(512) void gates2_k(
    unsigned short* qkv,
    const float* __restrict__ Wg, const float* __restrict__ bgp,
    const float* __restrict__ Wl, const float* __restrict__ blp,
    unsigned short* __restrict__ C1T){
  const int n  = blockIdx.x;
  const int bh = blockIdx.y;
  const int b = bh >> 1, h = bh & 1;
  const int tid = threadIdx.x;
  const int lane = tid & 63, w = tid >> 6;
  const size_t row0 = (size_t)(b*Tn + n*64);

  __shared__ unsigned short knl[64*512];   // 64 KB bf16 kn

  #pragma unroll
  for (int r=0; r<8; ++r){
    const int row = w*8 + r;
    const unsigned short* kr = qkv + (row0 + row)*QKVS + Dn + h*DKn + lane*8;
    ushort4 a = ((const ushort4*)kr)[0];
    ushort4 c = ((const ushort4*)kr)[1];
    float f0=bf2f(a.x), f1=bf2f(a.y), f2=bf2f(a.z), f3=bf2f(a.w);
    float f4=bf2f(c.x), f5=bf2f(c.y), f6=bf2f(c.z), f7=bf2f(c.w);
    float ss = f0*f0+f1*f1+f2*f2+f3*f3+f4*f4+f5*f5+f6*f6+f7*f7;
    #pragma unroll
    for (int m=1;m<64;m<<=1) ss += __shfl_xor(ss, m, 64);
    const float inv = 1.0f / fmaxf(sqrtf(ss), 1e-12f);
    u16x8 o;
    o[0]=f2bf(f0*inv); o[1]=f2bf(f1*inv); o[2]=f2bf(f2*inv); o[3]=f2bf(f3*inv);
    o[4]=f2bf(f4*inv); o[5]=f2bf(f5*inv); o[6]=f2bf(f6*inv); o[7]=f2bf(f7*inv);
    *(u16x8*)&knl[row*512 + lane*8] = o;
  }
  __syncthreads();

  const int kcol = tid;
  const int kidx = h*DKn + kcol;
  const float wg_ = Wg[kidx], bg_ = bgp[kidx], wl_ = Wl[kidx], bl_ = blp[kidx];

  u16x8 c1v[8];
  float p = 1.f;
  #pragma unroll
  for (int j=0;j<64;j++){
    float kn = bf2f(knl[j*512 + kcol]);
    float gam = 1.f/(1.f + __expf(-(wg_*kn + bg_)));
    float lam = 1.f/(1.f + __expf(-(wl_*kn + bl_)));
    float rh  = (1.f - lam)*gam;
    p *= rh;
    c1v[j>>3][j&7] = f2bf((1.f - rh)*kn / p);
    qkv[(row0 + j)*QKVS + Dn + kidx] = f2bf(p);   // P in place over k
  }
  unsigned short* c1dst = C1T + (((size_t)(bh*32+n))*DKn + kcol)*64;
  #pragma unroll
  for (int i=0;i<8;i++) ((u16x8*)c1dst)[i] = c1v[i];
}

// ---------------- yfused3: (n, bh, half) grid, 256 thr (4 waves) ----------------
// 1024 blocks, XCD-chunked: xcd=g&7 owns chunks n in [4*xcd,4*xcd+4) for all bh/half.
// Phase -1: wave w computes G row-group w (tril, verbatim mask) AND Gp row-group w
//           (full; zero for n==0), reusing the same qf registers; both into LDS
//           [64][64] bf16 with (row&7) granule-XOR swizzle.
// Phase  2: y = P (.) (pl*(Gp@C1(n-1)) + G@C1(n)) for this block's 256-kc half;
//           wave w -> output row-group w. C1 frags from global C1T (r14 layout).
// G/Gp computed twice globally (once per half) — +4.3 GF, trivial; buys 2x blocks
// and halved serial span per block (latency-bound kernel).
__global__ __launch_bounds__(256) void yfused3_k(
    const unsigned short* __restrict__ qkv,
    const unsigned short* __restrict__ C1T,
    unsigned short* __restrict__ ybuf){
  const int g    = blockIdx.x;           // 0..1023
  const int xcd  = g & 7;
  const int rest = g >> 3;               // 0..127
  const int bh   = rest & 15;
  const int nb   = (rest >> 4) & 3;      // 0..3
  const int half = rest >> 6;            // 0..1
  const int n    = xcd*4 + nb;           // bijective over 32 chunks
  const int b = bh >> 1, h = bh & 1;
  const int tid = threadIdx.x;
  const int lane = tid & 63, w = tid >> 6;   // w 0..3
  const int t0 = n*64;

  __shared__ unsigned short Gl[64*64];     // 8 KB
  __shared__ unsigned short Gpl[64*64];    // 8 KB

  const int g4 = lane >> 4, l16 = lane & 15;

  // ---- phase -1: wave w -> G row-group w (tril) then Gp row-group w (full) ----
  {
    const size_t arow = (size_t)(b*Tn + t0 + 16*w + l16)*QKVS + h*DKn;  // q rows
    bf16x8 qf[16];
    #pragma unroll
    for (int kst=0;kst<16;kst++) qf[kst] = *(const bf16x8*)(qkv + arow + kst*32 + g4*8);

    // G = tril(Q(n) @ V(n)^T), row-group w
    #pragma unroll
    for (int nt=0; nt<4; ++nt){
      f32x4 acc = (f32x4){0.f,0.f,0.f,0.f};
      if (nt <= w){
        const size_t brow = (size_t)(b*Tn + t0 + 16*nt + l16)*QKVS + 2*Dn + h*DKn;
        #pragma unroll
        for (int kst=0; kst<16; ++kst){
          bf16x8 bv = *(const bf16x8*)(qkv + brow + kst*32 + g4*8);
          acc = __builtin_amdgcn_mfma_f32_16x16x32_bf16(qf[kst], bv, acc, 0,0,0);
        }
      }
      #pragma unroll
      for (int r=0;r<4;r++){
        const int ii = 4*g4 + r;
        const int row_g = 16*w + ii;
        float val = acc[r];
        if (nt == w && l16 > ii) val = 0.f;
        const int col = 16*nt + l16;
        Gl[row_g*64 + (((col >> 3) ^ (row_g & 7)) << 3) + (col & 7)] = f2bf(val);
      }
    }
    // Gp = Q(n) @ V(n-1)^T, row-group w (zeros for n==0)
    const int tbp = (n > 0) ? (t0 - 64) : 0;
    #pragma unroll
    for (int nt=0; nt<4; ++nt){
      f32x4 acc = (f32x4){0.f,0.f,0.f,0.f};
      if (n > 0){
        const size_t brow = (size_t)(b*Tn + tbp + 16*nt + l16)*QKVS + 2*Dn + h*DKn;
        #pragma unroll
        for (int kst=0; kst<16; ++kst){
          bf16x8 bv = *(const bf16x8*)(qkv + brow + kst*32 + g4*8);
          acc = __builtin_amdgcn_mfma_f32_16x16x32_bf16(qf[kst], bv, acc, 0,0,0);
        }
      }
      #pragma unroll
      for (int r=0;r<4;r++){
        const int ii = 4*g4 + r;
        const int row_g = 16*w + ii;
        const int col = 16*nt + l16;
        Gpl[row_g*64 + (((col >> 3) ^ (row_g & 7)) << 3) + (col & 7)] = f2bf(acc[r]);
      }
    }
  }
  __syncthreads();

  // ---- phase 2: y = P (.) (pl*(Gp@C1prev) + G@C1cur), rows 16w.., cols half*256.. ----
  {
    const int l7 = l16 & 7;
    const int grow = (16*w + l16)*64;
    const bf16x8 ga0 = *(const bf16x8*)(Gl  + grow + ((g4     ^ l7) << 3));
    const bf16x8 ga1 = *(const bf16x8*)(Gl  + grow + (((4+g4) ^ l7) << 3));
    const bf16x8 gp0 = *(const bf16x8*)(Gpl + grow + ((g4     ^ l7) << 3));
    const bf16x8 gp1 = *(const bf16x8*)(Gpl + grow + (((4+g4) ^ l7) << 3));

    const int nprev = (n > 0) ? (n - 1) : 0;
    const size_t c1base = (((size_t)(bh*32 + n    ))*DKn + half*256)*64;
    const size_t cpbase = (((size_t)(bh*32 + nprev))*DKn + half*256)*64;
    const size_t plrow  = (size_t)(b*Tn + t0 - 1)*QKVS + Dn + h*DKn;

    f32x4 acc[16];
    #pragma unroll
    for (int kt=0;kt<16;kt++){
      const int kc = half*256 + kt*16 + l16;
      const size_t c1o = c1base + (size_t)(kt*16 + l16)*64;
      const size_t cpo = cpbase + (size_t)(kt*16 + l16)*64;
      bf16x8 bp0 = *(const bf16x8*)(C1T + cpo + g4*8);
      bf16x8 bp1 = *(const bf16x8*)(C1T + cpo + 32 + g4*8);
      bf16x8 b10 = *(const bf16x8*)(C1T + c1o + g4*8);
      bf16x8 b11 = *(const bf16x8*)(C1T + c1o + 32 + g4*8);
      f32x4 ap = (f32x4){0.f,0.f,0.f,0.f};
      f32x4 a  = (f32x4){0.f,0.f,0.f,0.f};
      ap = __builtin_amdgcn_mfma_f32_16x16x32_bf16(gp0, bp0, ap, 0,0,0);
      ap = __builtin_amdgcn_mfma_f32_16x16x32_bf16(gp1, bp1, ap, 0,0,0);
      a  = __builtin_amdgcn_mfma_f32_16x16x32_bf16(ga0, b10, a, 0,0,0);
      a  = __builtin_amdgcn_mfma_f32_16x16x32_bf16(ga1, b11, a, 0,0,0);
      float pl = (n > 0) ? bf2f(qkv[plrow + kc]) : 0.f;
      #pragma unroll
      for (int r=0;r<4;r++) acc[kt][r] = pl*ap[r] + a[r];
    }
    #pragma unroll
    for (int kt=0;kt<16;kt++){
      #pragma unroll
      for (int r=0;r<4;r++){
        const int i  = 16*w + 4*g4 + r;
        const int kc = half*256 + kt*16 + l16;
        const size_t row = (size_t)(b*Tn + t0 + i);
        float pv = bf2f(qkv[row*QKVS + Dn + h*DKn + kc]);
        ybuf[row*Dn + h*DKn + kc] = f2bf(pv*acc[kt][r]);
      }
    }
  }
}

extern "C" void kernel_launch(void* const* d_in, const int* in_sizes, int n_in,
                              void* d_out, int out_size, void* d_ws, size_t ws_size,
                              hipStream_t stream){
  const float* x  = (const float*)d_in[0];
  const float* Wq = (const float*)d_in[1];
  const float* Wk = (const float*)d_in[2];
  const float* Wv = (const float*)d_in[3];
  const float* Wo = (const float*)d_in[4];
  const float* Wg = (const float*)d_in[5];
  const float* bg = (const float*)d_in[6];
  const float* Wl = (const float*)d_in[7];
  const float* bl = (const float*)d_in[8];
  float* out = (float*)d_out;

  // workspace layout (total 176,160,768 B = 168.0 MiB)
  const size_t NEED = 176160768ull;
  if (ws_size < NEED) return;

  char* ws = (char*)d_ws;
  unsigned short* xb   = (unsigned short*)(ws);              // 32MB x bf16; later ybuf
  unsigned short* wqkv = (unsigned short*)(ws +  33554432);  // 6MB: Wq|Wk|Wv rows
  unsigned short* wob  = (unsigned short*)(ws +  39845888);  // 2MB
  unsigned short* qkv  = (unsigned short*)(ws +  41943040);  // 96MB [16384][3072]; k->P in place
  unsigned short* C1T  = (unsigned short*)(ws + 142606336);  // 32MB

  cast_all_k<<<20480, 256, 0, stream>>>(x, Wq, Wk, Wv, Wo, xb);

  // fused q|k|v projection: [16384][3072] = xb @ [Wq;Wk;Wv]^T ; 64 m x 24 n panels
  gemm_3r<true ><<<1536, 512, 0, stream>>>(xb, wqkv, qkv, BT, QKVS, Dn);

  gates2_k<<<dim3(32,16), 512, 0, stream>>>(qkv, Wg, bg, Wl, bl, C1T);

  // xb dead after projection -> reuse as ybuf
  yfused3_k<<<1024, 256, 0, stream>>>(qkv, C1T, xb);

  // 64 m x 8 n panels
  gemm_3r<false><<<512, 512, 0, stream>>>(xb, wob, out, BT, Dn, Dn);
}

// Round 23
// 280.345 us; speedup vs baseline: 1.1977x; 1.1977x over previous
//
#include <hip/hip_runtime.h>
#include <hip/hip_bf16.h>
#include <stdint.h>

#define Tn 2048
#define Dn 1024
#define DKn 512
#define Hn 2
#define Bn 8
#define BT (Bn*Tn)   // 16384
#define QKVS 3072

typedef __attribute__((ext_vector_type(8))) short bf16x8;
typedef __attribute__((ext_vector_type(4))) float f32x4;
typedef __attribute__((ext_vector_type(8))) unsigned short u16x8;

__device__ inline unsigned short f2bf(float f){
  unsigned u = __float_as_uint(f);
  u += 0x7fff + ((u >> 16) & 1);
  return (unsigned short)(u >> 16);
}
__device__ inline float bf2f(unsigned short u){
  return __uint_as_float(((unsigned)u) << 16);
}

// ---------------- fused cast: x|Wq|Wk|Wv|Wo -> contiguous bf16 region ----------------
__global__ __launch_bounds__(256) void cast_all_k(const float* __restrict__ x,
    const float* __restrict__ wq, const float* __restrict__ wk,
    const float* __restrict__ wv, const float* __restrict__ wo,
    unsigned short* __restrict__ out){
  int i = blockIdx.x*256 + threadIdx.x;   // 0..5242879
  const float* src; unsigned off;
  if      (i < 4194304){ src = x;  off = i; }
  else if (i < 4456448){ src = wq; off = i - 4194304; }
  else if (i < 4718592){ src = wk; off = i - 4456448; }
  else if (i < 4980736){ src = wv; off = i - 4718592; }
  else                 { src = wo; off = i - 4980736; }
  float4 f = ((const float4*)src)[off];
  ushort4 o;
  o.x = f2bf(f.x); o.y = f2bf(f.y); o.z = f2bf(f.z); o.w = f2bf(f.w);
  ((ushort4*)out)[i] = o;
}

#define GLOAD(src, dst) __builtin_amdgcn_global_load_lds( \
    (const __attribute__((address_space(1))) uint32_t*)(src), \
    (__attribute__((address_space(3))) uint32_t*)(dst), 16, 0, 0)

// ---------------- bf16 NT GEMM: 256x128 tile, 3-ring LDS, 1 barrier/K-tile ----------
// (verified passing at 911 TF, rounds 17-21)
template<bool BF16OUT>
__global__ __launch_bounds__(512) void gemm_3r(const unsigned short* __restrict__ A,
                                               const unsigned short* __restrict__ B,
                                               void* __restrict__ Cv, int M, int N, int K){
  __shared__ unsigned short As[3][256*64];
  __shared__ unsigned short Bs[3][128*64];
  const int tid  = threadIdx.x;
  const int lane = tid & 63;
  const int wid  = tid >> 6;          // 0..7
  const int wm = wid >> 1;            // 0..3 (64-row m group)
  const int wn = wid & 1;             // 0..1 (64-col n group)

  const int nmb = M >> 8, mpx = nmb >> 3;
  const int xcd = blockIdx.x & 7;
  const int lid = blockIdx.x >> 3;
  const int m0 = (xcd*mpx + (lid % mpx)) << 8;   // m-fastest within XCD chunk
  const int n0 = (lid / mpx) << 7;

  const int l15 = lane & 15, g4 = lane >> 4;
  const int r7  = l15 & 7;
  const int strow = tid >> 3;                       // 0..63
  const int stcol = (((tid & 7) ^ (strow & 7)) << 3);

  const unsigned short* pa[4];
  const unsigned short* pb[2];
  #pragma unroll
  for (int i=0;i<4;i++) pa[i] = A + (size_t)(m0 + i*64 + strow)*K + stcol;
  #pragma unroll
  for (int i=0;i<2;i++) pb[i] = B + (size_t)(n0 + i*64 + strow)*K + stcol;

  const int aoff = (wm*64 + l15)*64 + ((g4 ^ r7) << 3);
  const int boff = (wn*64 + l15)*64 + ((g4 ^ r7) << 3);
  const int aoffx = aoff ^ 32;    // ks=1 granule: (4+g4)^r7 on full offset
  const int boffx = boff ^ 32;
  const unsigned short* rA0  = &As[0][aoff];
  const unsigned short* rA1  = &As[1][aoff];
  const unsigned short* rA2  = &As[2][aoff];
  const unsigned short* rAx0 = &As[0][aoffx];
  const unsigned short* rAx1 = &As[1][aoffx];
  const unsigned short* rAx2 = &As[2][aoffx];
  const unsigned short* rB0  = &Bs[0][boff];
  const unsigned short* rB1  = &Bs[1][boff];
  const unsigned short* rB2  = &Bs[2][boff];
  const unsigned short* rBx0 = &Bs[0][boffx];
  const unsigned short* rBx1 = &Bs[1][boffx];
  const unsigned short* rBx2 = &Bs[2][boffx];
  unsigned short* sA0 = &As[0][tid*8];
  unsigned short* sA1 = &As[1][tid*8];
  unsigned short* sA2 = &As[2][tid*8];
  unsigned short* sB0 = &Bs[0][tid*8];
  unsigned short* sB1 = &Bs[1][tid*8];
  unsigned short* sB2 = &Bs[2][tid*8];

  f32x4 acc[4][4];
  #pragma unroll
  for (int m=0;m<4;m++)
    #pragma unroll
    for (int n=0;n<4;n++) acc[m][n] = (f32x4){0.f,0.f,0.f,0.f};

  const int NT = K >> 6;

#define STG3(SA, SB, kt) { \
    _Pragma("unroll") \
    for (int i_=0;i_<4;i_++) GLOAD(pa[i_] + (size_t)(kt)*64, (SA) + i_*4096); \
    _Pragma("unroll") \
    for (int i_=0;i_<2;i_++) GLOAD(pb[i_] + (size_t)(kt)*64, (SB) + i_*4096); \
  }

#define BODY(RA, RAX, RB, RBX, SA2_, SB2_, t) { \
    bf16x8 af[4][2], bfr[4][2]; \
    _Pragma("unroll") \
    for (int mf=0;mf<4;mf++){ \
      af[mf][0] = *(const bf16x8*)((RA)  + mf*1024); \
      af[mf][1] = *(const bf16x8*)((RAX) + mf*1024); \
    } \
    _Pragma("unroll") \
    for (int nf=0;nf<4;nf++){ \
      bfr[nf][0] = *(const bf16x8*)((RB)  + nf*1024); \
      bfr[nf][1] = *(const bf16x8*)((RBX) + nf*1024); \
    } \
    if ((t)+2 < NT) STG3(SA2_, SB2_, (t)+2) \
    __builtin_amdgcn_s_setprio(1); \
    _Pragma("unroll") \
    for (int ks=0;ks<2;ks++) \
      _Pragma("unroll") \
      for (int mf=0;mf<4;mf++) \
        _Pragma("unroll") \
        for (int nf=0;nf<4;nf++) \
          acc[mf][nf] = __builtin_amdgcn_mfma_f32_16x16x32_bf16(af[mf][ks], bfr[nf][ks], acc[mf][nf], 0,0,0); \
    __builtin_amdgcn_s_setprio(0); \
    if ((t) < NT-1){ \
      if ((t) < NT-2) asm volatile("s_waitcnt vmcnt(6) lgkmcnt(0)\n\ts_barrier" ::: "memory"); \
      else            asm volatile("s_waitcnt vmcnt(0) lgkmcnt(0)\n\ts_barrier" ::: "memory"); \
    } \
  }

  STG3(sA0, sB0, 0)
  STG3(sA1, sB1, 1)
  asm volatile("s_waitcnt vmcnt(6)\n\ts_barrier" ::: "memory");

  for (int tt=0; tt<15; tt+=3){
    BODY(rA0, rAx0, rB0, rBx0, sA2, sB2, tt)
    BODY(rA1, rAx1, rB1, rBx1, sA0, sB0, tt+1)
    BODY(rA2, rAx2, rB2, rBx2, sA1, sB1, tt+2)
  }
  BODY(rA0, rAx0, rB0, rBx0, sA2, sB2, 15)
#undef BODY
#undef STG3

  const int crow = (lane >> 4) * 4;
  const int ccol = (lane & 15);
  #pragma unroll
  for (int mf=0;mf<4;mf++)
    #pragma unroll
    for (int nf=0;nf<4;nf++)
      #pragma unroll
      for (int r=0;r<4;r++){
        size_t idx = (size_t)(m0 + wm*64 + mf*16 + crow + r)*N + (n0 + wn*64 + nf*16 + ccol);
        if constexpr (BF16OUT) ((unsigned short*)Cv)[idx] = f2bf(acc[mf][nf][r]);
        else                   ((float*)Cv)[idx] = acc[mf][nf][r];
      }
}

// ---------------- gates2: single k pass (kn via LDS transpose) + gates ----------------
// (verified round 21)
__global__ __launch_bounds__(512) void gates2_k(
    unsigned short* qkv,
    const float* __restrict__ Wg, const float* __restrict__ bgp,
    const float* __restrict__ Wl, const float* __restrict__ blp,
    unsigned short* __restrict__ C1T){
  const int n  = blockIdx.x;
  const int bh = blockIdx.y;
  const int b = bh >> 1, h = bh & 1;
  const int tid = threadIdx.x;
  const int lane = tid & 63, w = tid >> 6;
  const size_t row0 = (size_t)(b*Tn + n*64);

  __shared__ unsigned short knl[64*512];   // 64 KB bf16 kn

  #pragma unroll
  for (int r=0; r<8; ++r){
    const int row = w*8 + r;
    const unsigned short* kr = qkv + (row0 + row)*QKVS + Dn + h*DKn + lane*8;
    ushort4 a = ((const ushort4*)kr)[0];
    ushort4 c = ((const ushort4*)kr)[1];
    float f0=bf2f(a.x), f1=bf2f(a.y), f2=bf2f(a.z), f3=bf2f(a.w);
    float f4=bf2f(c.x), f5=bf2f(c.y), f6=bf2f(c.z), f7=bf2f(c.w);
    float ss = f0*f0+f1*f1+f2*f2+f3*f3+f4*f4+f5*f5+f6*f6+f7*f7;
    #pragma unroll
    for (int m=1;m<64;m<<=1) ss += __shfl_xor(ss, m, 64);
    const float inv = 1.0f / fmaxf(sqrtf(ss), 1e-12f);
    u16x8 o;
    o[0]=f2bf(f0*inv); o[1]=f2bf(f1*inv); o[2]=f2bf(f2*inv); o[3]=f2bf(f3*inv);
    o[4]=f2bf(f4*inv); o[5]=f2bf(f5*inv); o[6]=f2bf(f6*inv); o[7]=f2bf(f7*inv);
    *(u16x8*)&knl[row*512 + lane*8] = o;
  }
  __syncthreads();

  const int kcol = tid;
  const int kidx = h*DKn + kcol;
  const float wg_ = Wg[kidx], bg_ = bgp[kidx], wl_ = Wl[kidx], bl_ = blp[kidx];

  u16x8 c1v[8];
  float p = 1.f;
  #pragma unroll
  for (int j=0;j<64;j++){
    float kn = bf2f(knl[j*512 + kcol]);
    float gam = 1.f/(1.f + __expf(-(wg_*kn + bg_)));
    float lam = 1.f/(1.f + __expf(-(wl_*kn + bl_)));
    float rh  = (1.f - lam)*gam;
    p *= rh;
    c1v[j>>3][j&7] = f2bf((1.f - rh)*kn / p);
    qkv[(row0 + j)*QKVS + Dn + kidx] = f2bf(p);   // P in place over k
  }
  unsigned short* c1dst = C1T + (((size_t)(bh*32+n))*DKn + kcol)*64;
  #pragma unroll
  for (int i=0;i<8;i++) ((u16x8*)c1dst)[i] = c1v[i];
}

// ---------------- yfused2: G/Gp in LDS + y-GEMM (C1 from global) ----------------
// (verified round 21: 512 blocks x 512 thr, XCD-chunked decode)
__global__ __launch_bounds__(512) void yfused2_k(
    const unsigned short* __restrict__ qkv,
    const unsigned short* __restrict__ C1T,
    unsigned short* __restrict__ ybuf){
  const int g    = blockIdx.x;           // 0..511
  const int xcd  = g & 7;
  const int rest = g >> 3;               // 0..63
  const int bh   = rest & 15;
  const int nb   = rest >> 4;            // 0..3
  const int n    = xcd*4 + nb;           // bijective: 8 xcd x 4 = 32 chunks
  const int b = bh >> 1, h = bh & 1;
  const int tid = threadIdx.x;
  const int lane = tid & 63, w = tid >> 6;
  const int t0 = n*64;

  __shared__ unsigned short Gl[64*64];     // 8 KB
  __shared__ unsigned short Gpl[64*64];    // 8 KB

  const int g4 = lane >> 4, l16 = lane & 15;

  // ---- phase -1: G (waves 0-3, tril) / Gp (waves 4-7) into LDS ----
  {
    const int w4 = w & 3;
    const bool isG = (w < 4);
    const int tb = isG ? t0 : ((n > 0) ? (t0 - 64) : 0);
    const size_t arow = (size_t)(b*Tn + t0 + 16*w4 + l16)*QKVS + h*DKn;  // q rows
    bf16x8 qf[16];
    #pragma unroll
    for (int kst=0;kst<16;kst++) qf[kst] = *(const bf16x8*)(qkv + arow + kst*32 + g4*8);
    unsigned short* dst = isG ? Gl : Gpl;
    #pragma unroll
    for (int nt=0; nt<4; ++nt){
      f32x4 acc = (f32x4){0.f,0.f,0.f,0.f};
      const bool docomp = isG ? (nt <= w4) : (n > 0);
      if (docomp){
        const size_t brow = (size_t)(b*Tn + tb + 16*nt + l16)*QKVS + 2*Dn + h*DKn;  // v rows
        #pragma unroll
        for (int kst=0; kst<16; ++kst){
          bf16x8 bv = *(const bf16x8*)(qkv + brow + kst*32 + g4*8);
          acc = __builtin_amdgcn_mfma_f32_16x16x32_bf16(qf[kst], bv, acc, 0,0,0);
        }
      }
      #pragma unroll
      for (int r=0;r<4;r++){
        const int ii = 4*g4 + r;
        const int row_g = 16*w4 + ii;
        float val = acc[r];
        if (isG && nt == w4 && l16 > ii) val = 0.f;
        const int col = 16*nt + l16;
        dst[row_g*64 + (((col >> 3) ^ (row_g & 7)) << 3) + (col & 7)] = f2bf(val);
      }
    }
  }
  __syncthreads();

  // ---- phase 2: y = P (.) (pl*(Gp@C1prev) + G@C1cur) ----
  {
    const int wq = w & 3, half = w >> 2;
    const int l7 = l16 & 7;
    const int grow = (16*wq + l16)*64;
    const bf16x8 ga0 = *(const bf16x8*)(Gl  + grow + ((g4     ^ l7) << 3));
    const bf16x8 ga1 = *(const bf16x8*)(Gl  + grow + (((4+g4) ^ l7) << 3));
    const bf16x8 gp0 = *(const bf16x8*)(Gpl + grow + ((g4     ^ l7) << 3));
    const bf16x8 gp1 = *(const bf16x8*)(Gpl + grow + (((4+g4) ^ l7) << 3));

    const int nprev = (n > 0) ? (n - 1) : 0;
    const size_t c1base = (((size_t)(bh*32 + n    ))*DKn + half*256)*64;
    const size_t cpbase = (((size_t)(bh*32 + nprev))*DKn + half*256)*64;
    const size_t plrow  = (size_t)(b*Tn + t0 - 1)*QKVS + Dn + h*DKn;

    f32x4 acc[16];
    #pragma unroll
    for (int kt=0;kt<16;kt++){
      const int kc = half*256 + kt*16 + l16;
      const size_t c1o = c1base + (size_t)(kt*16 + l16)*64;
      const size_t cpo = cpbase + (size_t)(kt*16 + l16)*64;
      bf16x8 bp0 = *(const bf16x8*)(C1T + cpo + g4*8);
      bf16x8 bp1 = *(const bf16x8*)(C1T + cpo + 32 + g4*8);
      bf16x8 b10 = *(const bf16x8*)(C1T + c1o + g4*8);
      bf16x8 b11 = *(const bf16x8*)(C1T + c1o + 32 + g4*8);
      f32x4 ap = (f32x4){0.f,0.f,0.f,0.f};
      f32x4 a  = (f32x4){0.f,0.f,0.f,0.f};
      ap = __builtin_amdgcn_mfma_f32_16x16x32_bf16(gp0, bp0, ap, 0,0,0);
      ap = __builtin_amdgcn_mfma_f32_16x16x32_bf16(gp1, bp1, ap, 0,0,0);
      a  = __builtin_amdgcn_mfma_f32_16x16x32_bf16(ga0, b10, a, 0,0,0);
      a  = __builtin_amdgcn_mfma_f32_16x16x32_bf16(ga1, b11, a, 0,0,0);
      float pl = (n > 0) ? bf2f(qkv[plrow + kc]) : 0.f;
      #pragma unroll
      for (int r=0;r<4;r++) acc[kt][r] = pl*ap[r] + a[r];
    }
    #pragma unroll
    for (int kt=0;kt<16;kt++){
      #pragma unroll
      for (int r=0;r<4;r++){
        const int i  = 16*wq + 4*g4 + r;
        const int kc = half*256 + kt*16 + l16;
        const size_t row = (size_t)(b*Tn + t0 + i);
        float pv = bf2f(qkv[row*QKVS + Dn + h*DKn + kc]);
        ybuf[row*Dn + h*DKn + kc] = f2bf(pv*acc[kt][r]);
      }
    }
  }
}

extern "C" void kernel_launch(void* const* d_in, const int* in_sizes, int n_in,
                              void* d_out, int out_size, void* d_ws, size_t ws_size,
                              hipStream_t stream){
  const float* x  = (const float*)d_in[0];
  const float* Wq = (const float*)d_in[1];
  const float* Wk = (const float*)d_in[2];
  const float* Wv = (const float*)d_in[3];
  const float* Wo = (const float*)d_in[4];
  const float* Wg = (const float*)d_in[5];
  const float* bg = (const float*)d_in[6];
  const float* Wl = (const float*)d_in[7];
  const float* bl = (const float*)d_in[8];
  float* out = (float*)d_out;

  // workspace layout (total 176,160,768 B = 168.0 MiB)
  const size_t NEED = 176160768ull;
  if (ws_size < NEED) return;

  char* ws = (char*)d_ws;
  unsigned short* xb   = (unsigned short*)(ws);              // 32MB x bf16; later ybuf
  unsigned short* wqkv = (unsigned short*)(ws +  33554432);  // 6MB: Wq|Wk|Wv rows
  unsigned short* wob  = (unsigned short*)(ws +  39845888);  // 2MB
  unsigned short* qkv  = (unsigned short*)(ws +  41943040);  // 96MB [16384][3072]; k->P in place
  unsigned short* C1T  = (unsigned short*)(ws + 142606336);  // 32MB

  cast_all_k<<<20480, 256, 0, stream>>>(x, Wq, Wk, Wv, Wo, xb);

  // fused q|k|v projection: [16384][3072] = xb @ [Wq;Wk;Wv]^T ; 64 m x 24 n panels
  gemm_3r<true ><<<1536, 512, 0, stream>>>(xb, wqkv, qkv, BT, QKVS, Dn);

  gates2_k<<<dim3(32,16), 512, 0, stream>>>(qkv, Wg, bg, Wl, bl, C1T);

  // xb dead after projection -> reuse as ybuf
  yfused2_k<<<512, 512, 0, stream>>>(qkv, C1T, xb);

  // 64 m x 8 n panels
  gemm_3r<false><<<512, 512, 0, stream>>>(xb, wob, out, BT, Dn, Dn);
}

// Round 24
// 275.955 us; speedup vs baseline: 1.2168x; 1.0159x over previous
//
#include <hip/hip_runtime.h>
#include <hip/hip_bf16.h>
#include <stdint.h>

#define Tn 2048
#define Dn 1024
#define DKn 512
#define Hn 2
#define Bn 8
#define BT (Bn*Tn)   // 16384
#define QKVS 3072

typedef __attribute__((ext_vector_type(8))) short bf16x8;
typedef __attribute__((ext_vector_type(4))) float f32x4;
typedef __attribute__((ext_vector_type(8))) unsigned short u16x8;

__device__ inline unsigned short f2bf(float f){
  unsigned u = __float_as_uint(f);
  u += 0x7fff + ((u >> 16) & 1);
  return (unsigned short)(u >> 16);
}
__device__ inline float bf2f(unsigned short u){
  return __uint_as_float(((unsigned)u) << 16);
}

// ---------------- fused cast: x|Wq|Wk|Wv|Wo -> contiguous bf16 region ----------------
__global__ __launch_bounds__(256) void cast_all_k(const float* __restrict__ x,
    const float* __restrict__ wq, const float* __restrict__ wk,
    const float* __restrict__ wv, const float* __restrict__ wo,
    unsigned short* __restrict__ out){
  int i = blockIdx.x*256 + threadIdx.x;   // 0..5242879
  const float* src; unsigned off;
  if      (i < 4194304){ src = x;  off = i; }
  else if (i < 4456448){ src = wq; off = i - 4194304; }
  else if (i < 4718592){ src = wk; off = i - 4456448; }
  else if (i < 4980736){ src = wv; off = i - 4718592; }
  else                 { src = wo; off = i - 4980736; }
  float4 f = ((const float4*)src)[off];
  ushort4 o;
  o.x = f2bf(f.x); o.y = f2bf(f.y); o.z = f2bf(f.z); o.w = f2bf(f.w);
  ((ushort4*)out)[i] = o;
}

#define GLOAD(src, dst) __builtin_amdgcn_global_load_lds( \
    (const __attribute__((address_space(1))) uint32_t*)(src), \
    (__attribute__((address_space(3))) uint32_t*)(dst), 16, 0, 0)

// ---------------- bf16 NT GEMM: 256x128 tile, 3-ring LDS, 1 barrier/K-tile ----------
// (verified passing at 911 TF, rounds 17-23)
template<bool BF16OUT>
__global__ __launch_bounds__(512) void gemm_3r(const unsigned short* __restrict__ A,
                                               const unsigned short* __restrict__ B,
                                               void* __restrict__ Cv, int M, int N, int K){
  __shared__ unsigned short As[3][256*64];
  __shared__ unsigned short Bs[3][128*64];
  const int tid  = threadIdx.x;
  const int lane = tid & 63;
  const int wid  = tid >> 6;          // 0..7
  const int wm = wid >> 1;            // 0..3 (64-row m group)
  const int wn = wid & 1;             // 0..1 (64-col n group)

  const int nmb = M >> 8, mpx = nmb >> 3;
  const int xcd = blockIdx.x & 7;
  const int lid = blockIdx.x >> 3;
  const int m0 = (xcd*mpx + (lid % mpx)) << 8;   // m-fastest within XCD chunk
  const int n0 = (lid / mpx) << 7;

  const int l15 = lane & 15, g4 = lane >> 4;
  const int r7  = l15 & 7;
  const int strow = tid >> 3;                       // 0..63
  const int stcol = (((tid & 7) ^ (strow & 7)) << 3);

  const unsigned short* pa[4];
  const unsigned short* pb[2];
  #pragma unroll
  for (int i=0;i<4;i++) pa[i] = A + (size_t)(m0 + i*64 + strow)*K + stcol;
  #pragma unroll
  for (int i=0;i<2;i++) pb[i] = B + (size_t)(n0 + i*64 + strow)*K + stcol;

  const int aoff = (wm*64 + l15)*64 + ((g4 ^ r7) << 3);
  const int boff = (wn*64 + l15)*64 + ((g4 ^ r7) << 3);
  const int aoffx = aoff ^ 32;    // ks=1 granule: (4+g4)^r7 on full offset
  const int boffx = boff ^ 32;
  const unsigned short* rA0  = &As[0][aoff];
  const unsigned short* rA1  = &As[1][aoff];
  const unsigned short* rA2  = &As[2][aoff];
  const unsigned short* rAx0 = &As[0][aoffx];
  const unsigned short* rAx1 = &As[1][aoffx];
  const unsigned short* rAx2 = &As[2][aoffx];
  const unsigned short* rB0  = &Bs[0][boff];
  const unsigned short* rB1  = &Bs[1][boff];
  const unsigned short* rB2  = &Bs[2][boff];
  const unsigned short* rBx0 = &Bs[0][boffx];
  const unsigned short* rBx1 = &Bs[1][boffx];
  const unsigned short* rBx2 = &Bs[2][boffx];
  unsigned short* sA0 = &As[0][tid*8];
  unsigned short* sA1 = &As[1][tid*8];
  unsigned short* sA2 = &As[2][tid*8];
  unsigned short* sB0 = &Bs[0][tid*8];
  unsigned short* sB1 = &Bs[1][tid*8];
  unsigned short* sB2 = &Bs[2][tid*8];

  f32x4 acc[4][4];
  #pragma unroll
  for (int m=0;m<4;m++)
    #pragma unroll
    for (int n=0;n<4;n++) acc[m][n] = (f32x4){0.f,0.f,0.f,0.f};

  const int NT = K >> 6;

#define STG3(SA, SB, kt) { \
    _Pragma("unroll") \
    for (int i_=0;i_<4;i_++) GLOAD(pa[i_] + (size_t)(kt)*64, (SA) + i_*4096); \
    _Pragma("unroll") \
    for (int i_=0;i_<2;i_++) GLOAD(pb[i_] + (size_t)(kt)*64, (SB) + i_*4096); \
  }

#define BODY(RA, RAX, RB, RBX, SA2_, SB2_, t) { \
    bf16x8 af[4][2], bfr[4][2]; \
    _Pragma("unroll") \
    for (int mf=0;mf<4;mf++){ \
      af[mf][0] = *(const bf16x8*)((RA)  + mf*1024); \
      af[mf][1] = *(const bf16x8*)((RAX) + mf*1024); \
    } \
    _Pragma("unroll") \
    for (int nf=0;nf<4;nf++){ \
      bfr[nf][0] = *(const bf16x8*)((RB)  + nf*1024); \
      bfr[nf][1] = *(const bf16x8*)((RBX) + nf*1024); \
    } \
    if ((t)+2 < NT) STG3(SA2_, SB2_, (t)+2) \
    __builtin_amdgcn_s_setprio(1); \
    _Pragma("unroll") \
    for (int ks=0;ks<2;ks++) \
      _Pragma("unroll") \
      for (int mf=0;mf<4;mf++) \
        _Pragma("unroll") \
        for (int nf=0;nf<4;nf++) \
          acc[mf][nf] = __builtin_amdgcn_mfma_f32_16x16x32_bf16(af[mf][ks], bfr[nf][ks], acc[mf][nf], 0,0,0); \
    __builtin_amdgcn_s_setprio(0); \
    if ((t) < NT-1){ \
      if ((t) < NT-2) asm volatile("s_waitcnt vmcnt(6) lgkmcnt(0)\n\ts_barrier" ::: "memory"); \
      else            asm volatile("s_waitcnt vmcnt(0) lgkmcnt(0)\n\ts_barrier" ::: "memory"); \
    } \
  }

  STG3(sA0, sB0, 0)
  STG3(sA1, sB1, 1)
  asm volatile("s_waitcnt vmcnt(6)\n\ts_barrier" ::: "memory");

  for (int tt=0; tt<15; tt+=3){
    BODY(rA0, rAx0, rB0, rBx0, sA2, sB2, tt)
    BODY(rA1, rAx1, rB1, rBx1, sA0, sB0, tt+1)
    BODY(rA2, rAx2, rB2, rBx2, sA1, sB1, tt+2)
  }
  BODY(rA0, rAx0, rB0, rBx0, sA2, sB2, 15)
#undef BODY
#undef STG3

  const int crow = (lane >> 4) * 4;
  const int ccol = (lane & 15);
  #pragma unroll
  for (int mf=0;mf<4;mf++)
    #pragma unroll
    for (int nf=0;nf<4;nf++)
      #pragma unroll
      for (int r=0;r<4;r++){
        size_t idx = (size_t)(m0 + wm*64 + mf*16 + crow + r)*N + (n0 + wn*64 + nf*16 + ccol);
        if constexpr (BF16OUT) ((unsigned short*)Cv)[idx] = f2bf(acc[mf][nf][r]);
        else                   ((float*)Cv)[idx] = acc[mf][nf][r];
      }
}

// ---------------- gates2: single k pass (kn via LDS transpose) + gates ----------------
// (verified rounds 21/23)
__global__ __launch_bounds__(512) void gates2_k(
    unsigned short* qkv,
    const float* __restrict__ Wg, const float* __restrict__ bgp,
    const float* __restrict__ Wl, const float* __restrict__ blp,
    unsigned short* __restrict__ C1T){
  const int n  = blockIdx.x;
  const int bh = blockIdx.y;
  const int b = bh >> 1, h = bh & 1;
  const int tid = threadIdx.x;
  const int lane = tid & 63, w = tid >> 6;
  const size_t row0 = (size_t)(b*Tn + n*64);

  __shared__ unsigned short knl[64*512];   // 64 KB bf16 kn

  #pragma unroll
  for (int r=0; r<8; ++r){
    const int row = w*8 + r;
    const unsigned short* kr = qkv + (row0 + row)*QKVS + Dn + h*DKn + lane*8;
    ushort4 a = ((const ushort4*)kr)[0];
    ushort4 c = ((const ushort4*)kr)[1];
    float f0=bf2f(a.x), f1=bf2f(a.y), f2=bf2f(a.z), f3=bf2f(a.w);
    float f4=bf2f(c.x), f5=bf2f(c.y), f6=bf2f(c.z), f7=bf2f(c.w);
    float ss = f0*f0+f1*f1+f2*f2+f3*f3+f4*f4+f5*f5+f6*f6+f7*f7;
    #pragma unroll
    for (int m=1;m<64;m<<=1) ss += __shfl_xor(ss, m, 64);
    const float inv = 1.0f / fmaxf(sqrtf(ss), 1e-12f);
    u16x8 o;
    o[0]=f2bf(f0*inv); o[1]=f2bf(f1*inv); o[2]=f2bf(f2*inv); o[3]=f2bf(f3*inv);
    o[4]=f2bf(f4*inv); o[5]=f2bf(f5*inv); o[6]=f2bf(f6*inv); o[7]=f2bf(f7*inv);
    *(u16x8*)&knl[row*512 + lane*8] = o;
  }
  __syncthreads();

  const int kcol = tid;
  const int kidx = h*DKn + kcol;
  const float wg_ = Wg[kidx], bg_ = bgp[kidx], wl_ = Wl[kidx], bl_ = blp[kidx];

  u16x8 c1v[8];
  float p = 1.f;
  #pragma unroll
  for (int j=0;j<64;j++){
    float kn = bf2f(knl[j*512 + kcol]);
    float gam = 1.f/(1.f + __expf(-(wg_*kn + bg_)));
    float lam = 1.f/(1.f + __expf(-(wl_*kn + bl_)));
    float rh  = (1.f - lam)*gam;
    p *= rh;
    c1v[j>>3][j&7] = f2bf((1.f - rh)*kn / p);
    qkv[(row0 + j)*QKVS + Dn + kidx] = f2bf(p);   // P in place over k
  }
  unsigned short* c1dst = C1T + (((size_t)(bh*32+n))*DKn + kcol)*64;
  #pragma unroll
  for (int i=0;i<8;i++) ((u16x8*)c1dst)[i] = c1v[i];
}

// ---------------- yfused2: G/Gp in LDS + y-GEMM (C1 from global) ----------------
// (r21/r23 structure + this round: setprio around MFMA clusters (T5: 2 blocks/CU,
// phase-divergent -> scheduler has role diversity) and batch-hoisted pl loads
// (produced by previous dispatch -> legal before the LDS barrier; removes 16
// serialized global-load latencies from the epilogue chain).
__global__ __launch_bounds__(512) void yfused2_k(
    const unsigned short* __restrict__ qkv,
    const unsigned short* __restrict__ C1T,
    unsigned short* __restrict__ ybuf){
  const int g    = blockIdx.x;           // 0..511
  const int xcd  = g & 7;
  const int rest = g >> 3;               // 0..63
  const int bh   = rest & 15;
  const int nb   = rest >> 4;            // 0..3
  const int n    = xcd*4 + nb;           // bijective: 8 xcd x 4 = 32 chunks
  const int b = bh >> 1, h = bh & 1;
  const int tid = threadIdx.x;
  const int lane = tid & 63, w = tid >> 6;
  const int t0 = n*64;

  __shared__ unsigned short Gl[64*64];     // 8 KB
  __shared__ unsigned short Gpl[64*64];    // 8 KB

  const int g4 = lane >> 4, l16 = lane & 15;
  const int wq = w & 3, half = w >> 2;

  // batch-hoisted pl loads (chunk n-1 last-row P; independent of this kernel's LDS)
  const size_t plrow = (size_t)(b*Tn + t0 - 1)*QKVS + Dn + h*DKn;
  float plv[16];
  #pragma unroll
  for (int kt=0;kt<16;kt++){
    const int kc = half*256 + kt*16 + l16;
    plv[kt] = (n > 0) ? bf2f(qkv[plrow + kc]) : 0.f;
  }

  // ---- phase -1: G (waves 0-3, tril) / Gp (waves 4-7) into LDS ----
  {
    const int w4 = w & 3;
    const bool isG = (w < 4);
    const int tb = isG ? t0 : ((n > 0) ? (t0 - 64) : 0);
    const size_t arow = (size_t)(b*Tn + t0 + 16*w4 + l16)*QKVS + h*DKn;  // q rows
    bf16x8 qf[16];
    #pragma unroll
    for (int kst=0;kst<16;kst++) qf[kst] = *(const bf16x8*)(qkv + arow + kst*32 + g4*8);
    unsigned short* dst = isG ? Gl : Gpl;
    #pragma unroll
    for (int nt=0; nt<4; ++nt){
      f32x4 acc = (f32x4){0.f,0.f,0.f,0.f};
      const bool docomp = isG ? (nt <= w4) : (n > 0);
      if (docomp){
        const size_t brow = (size_t)(b*Tn + tb + 16*nt + l16)*QKVS + 2*Dn + h*DKn;  // v rows
        __builtin_amdgcn_s_setprio(1);
        #pragma unroll
        for (int kst=0; kst<16; ++kst){
          bf16x8 bv = *(const bf16x8*)(qkv + brow + kst*32 + g4*8);
          acc = __builtin_amdgcn_mfma_f32_16x16x32_bf16(qf[kst], bv, acc, 0,0,0);
        }
        __builtin_amdgcn_s_setprio(0);
      }
      #pragma unroll
      for (int r=0;r<4;r++){
        const int ii = 4*g4 + r;
        const int row_g = 16*w4 + ii;
        float val = acc[r];
        if (isG && nt == w4 && l16 > ii) val = 0.f;
        const int col = 16*nt + l16;
        dst[row_g*64 + (((col >> 3) ^ (row_g & 7)) << 3) + (col & 7)] = f2bf(val);
      }
    }
  }
  __syncthreads();

  // ---- phase 2: y = P (.) (pl*(Gp@C1prev) + G@C1cur) ----
  {
    const int l7 = l16 & 7;
    const int grow = (16*wq + l16)*64;
    const bf16x8 ga0 = *(const bf16x8*)(Gl  + grow + ((g4     ^ l7) << 3));
    const bf16x8 ga1 = *(const bf16x8*)(Gl  + grow + (((4+g4) ^ l7) << 3));
    const bf16x8 gp0 = *(const bf16x8*)(Gpl + grow + ((g4     ^ l7) << 3));
    const bf16x8 gp1 = *(const bf16x8*)(Gpl + grow + (((4+g4) ^ l7) << 3));

    const int nprev = (n > 0) ? (n - 1) : 0;
    const size_t c1base = (((size_t)(bh*32 + n    ))*DKn + half*256)*64;
    const size_t cpbase = (((size_t)(bh*32 + nprev))*DKn + half*256)*64;

    f32x4 acc[16];
    #pragma unroll
    for (int kt=0;kt<16;kt++){
      const size_t c1o = c1base + (size_t)(kt*16 + l16)*64;
      const size_t cpo = cpbase + (size_t)(kt*16 + l16)*64;
      bf16x8 bp0 = *(const bf16x8*)(C1T + cpo + g4*8);
      bf16x8 bp1 = *(const bf16x8*)(C1T + cpo + 32 + g4*8);
      bf16x8 b10 = *(const bf16x8*)(C1T + c1o + g4*8);
      bf16x8 b11 = *(const bf16x8*)(C1T + c1o + 32 + g4*8);
      f32x4 ap = (f32x4){0.f,0.f,0.f,0.f};
      f32x4 a  = (f32x4){0.f,0.f,0.f,0.f};
      __builtin_amdgcn_s_setprio(1);
      ap = __builtin_amdgcn_mfma_f32_16x16x32_bf16(gp0, bp0, ap, 0,0,0);
      ap = __builtin_amdgcn_mfma_f32_16x16x32_bf16(gp1, bp1, ap, 0,0,0);
      a  = __builtin_amdgcn_mfma_f32_16x16x32_bf16(ga0, b10, a, 0,0,0);
      a  = __builtin_amdgcn_mfma_f32_16x16x32_bf16(ga1, b11, a, 0,0,0);
      __builtin_amdgcn_s_setprio(0);
      #pragma unroll
      for (int r=0;r<4;r++) acc[kt][r] = plv[kt]*ap[r] + a[r];
    }
    #pragma unroll
    for (int kt=0;kt<16;kt++){
      #pragma unroll
      for (int r=0;r<4;r++){
        const int i  = 16*wq + 4*g4 + r;
        const int kc = half*256 + kt*16 + l16;
        const size_t row = (size_t)(b*Tn + t0 + i);
        float pv = bf2f(qkv[row*QKVS + Dn + h*DKn + kc]);
        ybuf[row*Dn + h*DKn + kc] = f2bf(pv*acc[kt][r]);
      }
    }
  }
}

extern "C" void kernel_launch(void* const* d_in, const int* in_sizes, int n_in,
                              void* d_out, int out_size, void* d_ws, size_t ws_size,
                              hipStream_t stream){
  const float* x  = (const float*)d_in[0];
  const float* Wq = (const float*)d_in[1];
  const float* Wk = (const float*)d_in[2];
  const float* Wv = (const float*)d_in[3];
  const float* Wo = (const float*)d_in[4];
  const float* Wg = (const float*)d_in[5];
  const float* bg = (const float*)d_in[6];
  const float* Wl = (const float*)d_in[7];
  const float* bl = (const float*)d_in[8];
  float* out = (float*)d_out;

  // workspace layout (total 176,160,768 B = 168.0 MiB)
  const size_t NEED = 176160768ull;
  if (ws_size < NEED) return;

  char* ws = (char*)d_ws;
  unsigned short* xb   = (unsigned short*)(ws);              // 32MB x bf16; later ybuf
  unsigned short* wqkv = (unsigned short*)(ws +  33554432);  // 6MB: Wq|Wk|Wv rows
  unsigned short* wob  = (unsigned short*)(ws +  39845888);  // 2MB
  unsigned short* qkv  = (unsigned short*)(ws +  41943040);  // 96MB [16384][3072]; k->P in place
  unsigned short* C1T  = (unsigned short*)(ws + 142606336);  // 32MB

  cast_all_k<<<20480, 256, 0, stream>>>(x, Wq, Wk, Wv, Wo, xb);

  // fused q|k|v projection: [16384][3072] = xb @ [Wq;Wk;Wv]^T ; 64 m x 24 n panels
  gemm_3r<true ><<<1536, 512, 0, stream>>>(xb, wqkv, qkv, BT, QKVS, Dn);

  gates2_k<<<dim3(32,16), 512, 0, stream>>>(qkv, Wg, bg, Wl, bl, C1T);

  // xb dead after projection -> reuse as ybuf
  yfused2_k<<<512, 512, 0, stream>>>(qkv, C1T, xb);

  // 64 m x 8 n panels
  gemm_3r<false><<<512, 512, 0, stream>>>(xb, wob, out, BT, Dn, Dn);
}